// Round 11
// baseline (596.717 us; speedup 1.0000x reference)
//
#include <hip/hip_runtime.h>
#include <hip/hip_fp16.h>
#include <hip/hip_cooperative_groups.h>
#include <cstddef>
#include <cstdint>

namespace cg = cooperative_groups;

#define NN 50000
#define DEG 8
#define EE (NN*DEG)
#define RT_CNT 3125   // NN/16 row-tiles
#define AG_CNT 1563   // ceil(NN/32) 32-row tiles for agg phases
#define KSTEPS 36     // K=1152 / 32:  [xt(4) | rel*16+tw*4+{Bm,mn,mx,std}]
#define W8L 18432     // Wcp layer stride in short8 units (KSTEPS*32*128/8)
#define MPAD 132      // f16 tile row pad (halves)
#define BUILD_BLKS 1563   // ceil(EE/256)

typedef __attribute__((ext_vector_type(8))) short short8;
typedef __attribute__((ext_vector_type(4))) float f32x4;

union Pack8 { __half h[8]; __half2 h2[4]; uint4 u; short8 s8; };

// ---------------------------------------------------------------------------
// K0w: combined-weight prep (R18 verbatim)
// ---------------------------------------------------------------------------
__global__ __launch_bounds__(256) void k_wprep(
    const float* __restrict__ post_W, const float* __restrict__ pre_W,
    const float* __restrict__ pre_b, const float* __restrict__ post_b,
    const float* __restrict__ lin_W, const float* __restrict__ lin_b,
    __half* __restrict__ Wcp, float* __restrict__ Qw, float* __restrict__ bc) {
    __shared__ float Pf[160 * 33];
    __shared__ float Wl[32 * 128];
    __shared__ float Wt[32 * 32];
    __shared__ float Ps[32 * 32];
    __shared__ float Q[32 * 32];
    __shared__ float T3s[32];
    int tid = threadIdx.x;
    int m4 = blockIdx.x;
    int l = m4 >> 3, r = (m4 >> 2) & 1, tw = m4 & 3;
    const float* PW = post_W + (size_t)m4 * 416 * 32;
    for (int i = tid; i < 160 * 32; i += 256) {
        int row = i >> 5, g = i & 31;
        float v;
        if (row < 32) v = PW[row * 32 + g];
        else {
            int rr = row - 32;
            v = PW[(32 + rr) * 32 + g] + PW[(160 + rr) * 32 + g] + PW[(288 + rr) * 32 + g];
        }
        Pf[row * 33 + g] = v;
    }
    for (int i = tid; i < 1024; i += 256) Wt[i] = pre_W[(size_t)m4 * 2048 + i];
    for (int i = tid; i < 4096; i += 256)
        Wl[i] = lin_W[(size_t)(l * 2 + r) * 16384 + tw * 32 * 128 + i];
    __syncthreads();
    for (int i = tid; i < 1024; i += 256) {
        int g = i >> 5, j = i & 31;
        Ps[i] = Pf[(32 + g) * 33 + j] + Pf[(64 + g) * 33 + j] + Pf[(96 + g) * 33 + j];
    }
    __syncthreads();
    for (int i = tid; i < 1024; i += 256) {
        int f = i >> 5, j = i & 31;
        float acc = Pf[f * 33 + j];
#pragma unroll
        for (int g = 0; g < 32; g++) acc += Wt[f * 32 + g] * Ps[g * 32 + j];
        Q[i] = acc;
    }
    if (tid < 32) {
        int j = tid;
        float v = post_b[m4 * 32 + j];
#pragma unroll
        for (int g = 0; g < 32; g++) v += pre_b[m4 * 32 + g] * Ps[g * 32 + j];
        T3s[j] = v;
    }
    __syncthreads();
    for (int u = tid; u < 2048; u += 256) {
        int lane = u & 63, t = (u >> 6) & 7, s = u >> 9;
        int quad = lane >> 4, nl = lane & 15;
        int n = t * 16 + nl;
        Pack8 pk;
#pragma unroll
        for (int e = 0; e < 8; e++) {
            int f = quad * 8 + e;
            const float* Pr = &Pf[((s + 1) * 32 + f) * 33];
            float acc = 0.f;
#pragma unroll
            for (int j = 0; j < 32; j++) acc += Pr[j] * Wl[j * 128 + n];
            pk.h[e] = __float2half(acc);
        }
        int ks = 4 + r * 16 + tw * 4 + s;
        *(uint4*)&Wcp[((size_t)l * W8L + (t * KSTEPS + ks) * 64 + lane) * 8] = pk.u;
    }
    for (int i = tid; i < 4096; i += 256) {
        int f = i >> 7, n = i & 127;
        float acc = 0.f;
#pragma unroll
        for (int j = 0; j < 32; j++) acc += Q[f * 32 + j] * Wl[j * 128 + n];
        atomicAdd(&Qw[(size_t)l * 16384 + (tw * 32 + f) * 128 + n], acc);
    }
    if (tid < 128) {
        float v = 0.f;
#pragma unroll
        for (int j = 0; j < 32; j++) v += T3s[j] * Wl[j * 128 + tid];
        atomicAdd(&bc[l * 128 + tid], v);
        if ((m4 & 7) == 0)
            atomicAdd(&bc[l * 128 + tid],
                      lin_b[(2 * l) * 128 + tid] + lin_b[(2 * l + 1) * 128 + tid]);
    }
}

// ---------------------------------------------------------------------------
// K_prep2: merged rev-neighbor build + all weight packs (R18 verbatim)
// ---------------------------------------------------------------------------
__global__ void k_prep2(const int* __restrict__ ef, int* __restrict__ cnt,
                        int* __restrict__ rev_nbr,
                        const float* __restrict__ Qw, __half* __restrict__ Wcp,
                        const float* __restrict__ W_in, __half* __restrict__ Winp,
                        const float* __restrict__ mlp_W1, __half* __restrict__ W1p,
                        const float* __restrict__ mlp_W2, __half* __restrict__ W2p,
                        const float* __restrict__ pre_W, __half* __restrict__ WbBD) {
    int b = blockIdx.x, tid = threadIdx.x;
    if (b < BUILD_BLKS) {
        int e = b * 256 + tid;
        if (e < EE) {
            int s = ef[e], d = ef[EE + e];
            int q = atomicAdd(&cnt[s], 1);
            rev_nbr[s * DEG + q] = d;
        }
        return;
    }
    int gid = (b - BUILD_BLKS) * 256 + tid;
    if (gid < 4096) {
        int lane = gid & 63, t = (gid >> 6) & 7, ks = (gid >> 9) & 3, l = gid >> 11;
        int quad = lane >> 4;
        int n = t * 16 + (lane & 15);
        Pack8 pk;
#pragma unroll
        for (int e = 0; e < 8; e++)
            pk.h[e] = __float2half(Qw[(size_t)l * 16384 + (ks * 32 + quad * 8 + e) * 128 + n]);
        *(uint4*)&Wcp[((size_t)l * W8L + (t * KSTEPS + ks) * 64 + lane) * 8] = pk.u;
        return;
    }
    if (gid < 8704) {
        const float* W; __half* dst; int id;
        if (gid < 6144)      { W = W_in;   dst = Winp; id = gid - 4096; }
        else if (gid < 8192) { W = mlp_W1; dst = W1p;  id = gid - 6144; }
        else                 { W = mlp_W2; dst = W2p;  id = gid - 8192; }
        int N = (gid < 8192) ? 128 : 32;
        int lane = id & 63;
        int ks = (id >> 6) & 3;
        int t = (id >> 6) >> 2;
        int quad = lane >> 4, nl = lane & 15;
        int n = t * 16 + nl;
        Pack8 pk;
#pragma unroll
        for (int e = 0; e < 8; e++)
            pk.h[e] = __float2half(W[(size_t)(ks * 32 + quad * 8 + e) * N + n]);
        *(uint4*)&dst[(size_t)id * 8] = pk.u;
        return;
    }
    {
        int id = gid - 8704;
        if (id >= 8192) return;
        int lane = id & 63, ks = (id >> 6) & 3, t8 = (id >> 8) & 7;
        int rel = (id >> 11) & 1, l = id >> 12;
        int quad = lane >> 4, nl = lane & 15;
        int n = t8 * 16 + nl;
        int tn = n >> 5;
        Pack8 pk;
#pragma unroll
        for (int e = 0; e < 8; e++) {
            int k = ks * 32 + quad * 8 + e;
            float v = 0.f;
            if ((k >> 5) == tn)
                v = pre_W[(size_t)((((l * 2 + rel) * 4 + tn) * 64) + 32 + (k & 31)) * 32 + (n & 31)];
            pk.h[e] = __float2half(v);
        }
        *(uint4*)&WbBD[((size_t)(l * 2 + rel) * 2048 + (t8 * 4 + ks) * 64 + lane) * 8] = pk.u;
    }
}

// ---------------------------------------------------------------------------
// Phase bodies: NOINLINE so the mega-kernel's register allocation is
// max-of-phases, not the inlined union (R17's spill cause). No live state
// crosses these calls (all in global/LDS).
// ---------------------------------------------------------------------------
__device__ __attribute__((noinline)) void in_fused_wave(
    int rt, int lane, const float* __restrict__ X, const __half* __restrict__ Wp,
    const float* __restrict__ b, const __half* __restrict__ WbBDp,
    __half* __restrict__ H, __half* __restrict__ Bplanes, __half* T) {
    int mm = lane & 15, quad = lane >> 4;
    short8 a[4];
#pragma unroll
    for (int ks = 0; ks < 4; ks++) {
        const float4* p = (const float4*)&X[(size_t)(rt * 16 + mm) * 128 + ks * 32 + quad * 8];
        float4 v0 = p[0], v1 = p[1];
        Pack8 pk;
        pk.h[0] = __float2half(v0.x); pk.h[1] = __float2half(v0.y);
        pk.h[2] = __float2half(v0.z); pk.h[3] = __float2half(v0.w);
        pk.h[4] = __float2half(v1.x); pk.h[5] = __float2half(v1.y);
        pk.h[6] = __float2half(v1.z); pk.h[7] = __float2half(v1.w);
        a[ks] = pk.s8;
    }
    const short8* Bb = (const short8*)Wp + lane;
    f32x4 acc[8];
#pragma unroll
    for (int t = 0; t < 8; t++) acc[t] = (f32x4){0.f, 0.f, 0.f, 0.f};
#pragma unroll
    for (int ks = 0; ks < 4; ks++)
#pragma unroll
        for (int t = 0; t < 8; t++)
            acc[t] = __builtin_amdgcn_mfma_f32_16x16x32_f16(
                a[ks], Bb[(t * 4 + ks) * 64], acc[t], 0, 0, 0);
#pragma unroll
    for (int t = 0; t < 8; t++) {
        int n = t * 16 + mm;
        float bias = b[n];
#pragma unroll
        for (int r = 0; r < 4; r++)
            T[(quad * 4 + r) * MPAD + n] = __float2half(fmaxf(acc[t][r] + bias, 0.f));
    }
#pragma unroll
    for (int it = 0; it < 4; it++) {
        int idx = it * 64 + lane;
        int row = idx >> 4, col = (idx & 15) * 8;
        *(uint4*)&H[(size_t)(rt * 16 + row) * 128 + col] = *(uint4*)&T[row * MPAD + col];
    }
    short8 a2[4];
#pragma unroll
    for (int ks = 0; ks < 4; ks++)
        a2[ks] = *(const short8*)&T[mm * MPAD + ks * 32 + quad * 8];
#pragma unroll
    for (int rel = 0; rel < 2; rel++) {
        const short8* Bd = (const short8*)WbBDp + (size_t)rel * 2048 + lane;
        f32x4 ac[8];
#pragma unroll
        for (int t = 0; t < 8; t++) ac[t] = (f32x4){0.f, 0.f, 0.f, 0.f};
#pragma unroll
        for (int ks = 0; ks < 4; ks++)
#pragma unroll
            for (int t = 0; t < 8; t++)
                ac[t] = __builtin_amdgcn_mfma_f32_16x16x32_f16(
                    a2[ks], Bd[(t * 4 + ks) * 64], ac[t], 0, 0, 0);
#pragma unroll
        for (int t = 0; t < 8; t++) {
            int n = t * 16 + mm;
#pragma unroll
            for (int r = 0; r < 4; r++)
                T[(quad * 4 + r) * MPAD + n] = __float2half(ac[t][r]);
        }
        __half* Bp = Bplanes + (size_t)rel * NN * 128;
#pragma unroll
        for (int it = 0; it < 4; it++) {
            int idx = it * 64 + lane;
            int row = idx >> 4, col = (idx & 15) * 8;
            *(uint4*)&Bp[(size_t)(rt * 16 + row) * 128 + col] = *(uint4*)&T[row * MPAD + col];
        }
    }
}

__device__ __attribute__((noinline)) void preB_wave(
    int rt, int lane, const float* __restrict__ Yf,
    const float* __restrict__ sc, const float* __restrict__ sh,
    __half* __restrict__ Hout, const __half* __restrict__ WbBDp,
    __half* __restrict__ Bplanes, __half* T) {
    int mm = lane & 15, quad = lane >> 4;
    short8 a[4];
#pragma unroll
    for (int ks = 0; ks < 4; ks++) {
        int c0 = ks * 32 + quad * 8;
        size_t base = (size_t)(rt * 16 + mm) * 128 + c0;
        const float4* p = (const float4*)&Yf[base];
        float4 v0 = p[0], v1 = p[1];
        float4 s0 = *(const float4*)&sc[c0], s1 = *(const float4*)&sc[c0 + 4];
        float4 f0 = *(const float4*)&sh[c0], f1 = *(const float4*)&sh[c0 + 4];
        Pack8 pk;
        pk.h[0] = __float2half(fmaxf(s0.x * v0.x + f0.x, 0.f));
        pk.h[1] = __float2half(fmaxf(s0.y * v0.y + f0.y, 0.f));
        pk.h[2] = __float2half(fmaxf(s0.z * v0.z + f0.z, 0.f));
        pk.h[3] = __float2half(fmaxf(s0.w * v0.w + f0.w, 0.f));
        pk.h[4] = __float2half(fmaxf(s1.x * v1.x + f1.x, 0.f));
        pk.h[5] = __float2half(fmaxf(s1.y * v1.y + f1.y, 0.f));
        pk.h[6] = __float2half(fmaxf(s1.z * v1.z + f1.z, 0.f));
        pk.h[7] = __float2half(fmaxf(s1.w * v1.w + f1.w, 0.f));
        *(uint4*)&Hout[base] = pk.u;
        a[ks] = pk.s8;
    }
#pragma unroll
    for (int rel = 0; rel < 2; rel++) {
        const short8* Bb = (const short8*)WbBDp + (size_t)rel * 2048 + lane;
        f32x4 acc[8];
#pragma unroll
        for (int t = 0; t < 8; t++) acc[t] = (f32x4){0.f, 0.f, 0.f, 0.f};
#pragma unroll
        for (int ks = 0; ks < 4; ks++)
#pragma unroll
            for (int t = 0; t < 8; t++)
                acc[t] = __builtin_amdgcn_mfma_f32_16x16x32_f16(
                    a[ks], Bb[(t * 4 + ks) * 64], acc[t], 0, 0, 0);
#pragma unroll
        for (int t = 0; t < 8; t++) {
            int n = t * 16 + mm;
#pragma unroll
            for (int r = 0; r < 4; r++)
                T[(quad * 4 + r) * MPAD + n] = __float2half(acc[t][r]);
        }
        __half* Bp = Bplanes + (size_t)rel * NN * 128;
#pragma unroll
        for (int it = 0; it < 4; it++) {
            int idx = it * 64 + lane;
            int row = idx >> 4, col = (idx & 15) * 8;
            *(uint4*)&Bp[(size_t)(rt * 16 + row) * 128 + col] = *(uint4*)&T[row * MPAD + col];
        }
    }
}

__device__ __attribute__((noinline)) void mlp_wave(
    int rt, int lane, const float* __restrict__ Yb,
    const float* __restrict__ sc, const float* __restrict__ sh,
    const __half* __restrict__ W1p, const float* __restrict__ b1,
    const __half* __restrict__ W2p, const float* __restrict__ b2,
    float* __restrict__ out, __half* T) {
    int mm = lane & 15, quad = lane >> 4;
    short8 a[4];
#pragma unroll
    for (int ks = 0; ks < 4; ks++) {
        int c0 = ks * 32 + quad * 8;
        const float4* p = (const float4*)&Yb[(size_t)(rt * 16 + mm) * 128 + c0];
        float4 v0 = p[0], v1 = p[1];
        float4 s0 = *(const float4*)&sc[c0], s1 = *(const float4*)&sc[c0 + 4];
        float4 f0 = *(const float4*)&sh[c0], f1 = *(const float4*)&sh[c0 + 4];
        Pack8 pk;
        pk.h[0] = __float2half(fmaxf(s0.x * v0.x + f0.x, 0.f));
        pk.h[1] = __float2half(fmaxf(s0.y * v0.y + f0.y, 0.f));
        pk.h[2] = __float2half(fmaxf(s0.z * v0.z + f0.z, 0.f));
        pk.h[3] = __float2half(fmaxf(s0.w * v0.w + f0.w, 0.f));
        pk.h[4] = __float2half(fmaxf(s1.x * v1.x + f1.x, 0.f));
        pk.h[5] = __float2half(fmaxf(s1.y * v1.y + f1.y, 0.f));
        pk.h[6] = __float2half(fmaxf(s1.z * v1.z + f1.z, 0.f));
        pk.h[7] = __float2half(fmaxf(s1.w * v1.w + f1.w, 0.f));
        a[ks] = pk.s8;
    }
    const short8* B1 = (const short8*)W1p + lane;
    f32x4 acc[8];
#pragma unroll
    for (int t = 0; t < 8; t++) acc[t] = (f32x4){0.f, 0.f, 0.f, 0.f};
#pragma unroll
    for (int ks = 0; ks < 4; ks++)
#pragma unroll
        for (int t = 0; t < 8; t++)
            acc[t] = __builtin_amdgcn_mfma_f32_16x16x32_f16(
                a[ks], B1[(t * 4 + ks) * 64], acc[t], 0, 0, 0);
#pragma unroll
    for (int t = 0; t < 8; t++) {
        int n = t * 16 + mm;
        float bias = b1[n];
#pragma unroll
        for (int r = 0; r < 4; r++)
            T[(quad * 4 + r) * MPAD + n] = __float2half(fmaxf(acc[t][r] + bias, 0.f));
    }
    short8 a2[4];
#pragma unroll
    for (int ks = 0; ks < 4; ks++)
        a2[ks] = *(const short8*)&T[mm * MPAD + ks * 32 + quad * 8];
    const short8* B2 = (const short8*)W2p + lane;
    f32x4 acc2[2];
#pragma unroll
    for (int t = 0; t < 2; t++) acc2[t] = (f32x4){0.f, 0.f, 0.f, 0.f};
#pragma unroll
    for (int ks = 0; ks < 4; ks++)
#pragma unroll
        for (int t = 0; t < 2; t++)
            acc2[t] = __builtin_amdgcn_mfma_f32_16x16x32_f16(
                a2[ks], B2[(t * 4 + ks) * 64], acc2[t], 0, 0, 0);
#pragma unroll
    for (int t = 0; t < 2; t++) {
        int n = t * 16 + mm;
        float bias = b2[n];
#pragma unroll
        for (int r = 0; r < 4; r++)
            out[(size_t)(rt * 16 + quad * 4 + r) * 32 + n] = acc2[t][r] + bias;
    }
}

__device__ __attribute__((noinline)) void agg_tile(
    int blk, int tid, const __half* __restrict__ hbuf,
    const __half* __restrict__ Bplanes,
    const int* __restrict__ fwd_nbr, const int* __restrict__ rev_nbr,
    const __half* __restrict__ Wcp, const float* __restrict__ bc,
    float* __restrict__ Y, float* __restrict__ bnsum, float* __restrict__ bnsum2,
    __half* __restrict__ Spack) {
    int lane = tid & 63, wv = tid >> 6;
    int G = tid >> 4;
    int f16 = tid & 15;
    int tw = f16 >> 2, quad = f16 & 3;
    int fo = f16 * 8;
    int pos = quad * 32 + (G ^ quad ^ ((tw & 1) << 2));
    int mB = lane & 15, qB = lane >> 4;
    int t = wv;
    int nodeg = blk * 32 + G;
    if (nodeg >= NN) nodeg = NN - 1;

    Pack8 axt[2][4];
#pragma unroll
    for (int mt = 0; mt < 2; mt++) {
        int nd = blk * 32 + mt * 16 + mB;
        if (nd >= NN) nd = NN - 1;
#pragma unroll
        for (int ks = 0; ks < 4; ks++)
            axt[mt][ks].u = *(const uint4*)&hbuf[(size_t)nd * 128 + ks * 32 + qB * 8];
    }
    {
        const int4* nf = (const int4*)&fwd_nbr[nodeg * 8];
        const int4* nr = (const int4*)&rev_nbr[nodeg * 8];
        int4 a0 = nf[0], a1 = nf[1], b0v = nr[0], b1v = nr[1];
        int idx0[8] = {a0.x, a0.y, a0.z, a0.w, a1.x, a1.y, a1.z, a1.w};
        int idx1[8] = {b0v.x, b0v.y, b0v.z, b0v.w, b1v.x, b1v.y, b1v.z, b1v.w};
        Pack8 r0[8], r1[8];
        const __half* Bp1 = Bplanes + (size_t)NN * 128;
#pragma unroll
        for (int k = 0; k < 8; k++)
            r0[k].u = *(const uint4*)&Bplanes[(size_t)idx0[k] * 128 + fo];
#pragma unroll
        for (int k = 0; k < 8; k++)
            r1[k].u = *(const uint4*)&Bp1[(size_t)idx1[k] * 128 + fo];
#pragma unroll
        for (int rel = 0; rel < 2; rel++) {
            Pack8* rr = rel ? r1 : r0;
            float sS[8], qS[8], mnS[8], mxS[8];
#pragma unroll
            for (int j = 0; j < 8; j++) {
                sS[j] = 0.f; qS[j] = 0.f; mnS[j] = 1e30f; mxS[j] = -1e30f;
            }
#pragma unroll
            for (int k = 0; k < 8; k++) {
#pragma unroll
                for (int j2 = 0; j2 < 4; j2++) {
                    __half2 h = rr[k].h2[j2];
                    float a = __half2float(__low2half(h));
                    float b = __half2float(__high2half(h));
                    int j0 = 2 * j2, j1 = j0 + 1;
                    sS[j0] += a; qS[j0] += a * a;
                    mnS[j0] = fminf(mnS[j0], a); mxS[j0] = fmaxf(mxS[j0], a);
                    sS[j1] += b; qS[j1] += b * b;
                    mnS[j1] = fminf(mnS[j1], b); mxS[j1] = fmaxf(mxS[j1], b);
                }
            }
            Pack8 mean, stdv, mnp, mxp;
#pragma unroll
            for (int j = 0; j < 8; j++) {
                float Bm = sS[j] * 0.125f;
                mean.h[j] = __float2half(Bm);
                stdv.h[j] = __float2half(
                    sqrtf(fmaxf(qS[j] * 0.125f - Bm * Bm, 0.f) + 1e-5f));
                mnp.h[j] = __float2half(mnS[j]);
                mxp.h[j] = __float2half(mxS[j]);
            }
            int ksb = rel * 16 + tw * 4;
            *(uint4*)&Spack[((size_t)(ksb + 0) * 128 + pos) * 8] = mean.u;
            *(uint4*)&Spack[((size_t)(ksb + 1) * 128 + pos) * 8] = mnp.u;
            *(uint4*)&Spack[((size_t)(ksb + 2) * 128 + pos) * 8] = mxp.u;
            *(uint4*)&Spack[((size_t)(ksb + 3) * 128 + pos) * 8] = stdv.u;
        }
    }
    __syncthreads();
    const short8* Bb = (const short8*)Wcp + lane;
    f32x4 acc0 = (f32x4){0.f, 0.f, 0.f, 0.f};
    f32x4 acc1 = (f32x4){0.f, 0.f, 0.f, 0.f};
    short8 p[6];
#pragma unroll
    for (int dd = 0; dd < 6; dd++) p[dd] = Bb[((size_t)t * KSTEPS + dd) * 64];
    __builtin_amdgcn_s_setprio(1);
#pragma unroll
    for (int ks = 0; ks < KSTEPS; ks++) {
        short8 a0f, a1f;
        if (ks < 4) {
            a0f = axt[0][ks].s8;
            a1f = axt[1][ks].s8;
        } else {
            int ss = ks - 4;
            int twk = (ss >> 2) & 3;
            int posr = qB * 32 + (mB ^ qB ^ ((twk & 1) << 2));
            const __half* row = &Spack[((size_t)ss * 128 + posr) * 8];
            a0f = *(const short8*)row;
            a1f = *(const short8*)(row + 16 * 8);
        }
        acc0 = __builtin_amdgcn_mfma_f32_16x16x32_f16(a0f, p[ks % 6], acc0, 0, 0, 0);
        acc1 = __builtin_amdgcn_mfma_f32_16x16x32_f16(a1f, p[ks % 6], acc1, 0, 0, 0);
        if (ks + 6 < KSTEPS) p[ks % 6] = Bb[((size_t)t * KSTEPS + ks + 6) * 64];
    }
    __builtin_amdgcn_s_setprio(0);
#pragma unroll
    for (int mt = 0; mt < 2; mt++) {
        f32x4 acc = mt ? acc1 : acc0;
        int n = t * 16 + mB;
        float bias = bc[n];
        float ls = 0.f, ls2 = 0.f;
#pragma unroll
        for (int r = 0; r < 4; r++) {
            int node = blk * 32 + mt * 16 + qB * 4 + r;
            if (node < NN) {
                float v = acc[r] + bias;
                Y[(size_t)node * 128 + n] = v;
                ls += v; ls2 += v * v;
            }
        }
        ls += __shfl_xor(ls, 16); ls += __shfl_xor(ls, 32);
        ls2 += __shfl_xor(ls2, 16); ls2 += __shfl_xor(ls2, 32);
        if (qB == 0) {
            atomicAdd(&bnsum[n], ls);
            atomicAdd(&bnsum2[n], ls2);
        }
    }
}

// ---------------------------------------------------------------------------
// K_mega: cooperative whole-network kernel (R17 structure, noinline phases):
//  P1 in_fused  P2 agg l0  P3 preB  P4 agg l1  P5 mlp, grid.sync between.
// ---------------------------------------------------------------------------
__global__ __launch_bounds__(512) void k_mega(
    const float* __restrict__ X, const __half* __restrict__ Winp,
    const float* __restrict__ b_in, const __half* __restrict__ WbBD,
    __half* __restrict__ hbuf, __half* __restrict__ Bpl,
    const __half* __restrict__ Wcp,
    const int* __restrict__ fwd_nbr, const int* __restrict__ rev_nbr,
    const float* __restrict__ bc, float* __restrict__ ybuf,
    float* __restrict__ bns, const float* __restrict__ bn_g,
    const float* __restrict__ bn_b,
    const __half* __restrict__ W1p, const float* __restrict__ b1,
    const __half* __restrict__ W2p, const float* __restrict__ b2,
    float* __restrict__ out) {
    __shared__ __half Spack[32 * 128 * 8];   // 65,536 B
    __shared__ float sc[128], sh[128];
    cg::grid_group grid = cg::this_grid();
    int tid = threadIdx.x, blk = blockIdx.x, nblk = gridDim.x;
    int wv = tid >> 6, lane = tid & 63;
    __half* T = Spack + (size_t)wv * 16 * MPAD;  // per-wave 4224-B slice

    // ---- P1: input layer + layer-0 B planes ----
    for (int rt = blk * 8 + wv; rt < RT_CNT; rt += nblk * 8)
        in_fused_wave(rt, lane, X, Winp, b_in, WbBD, hbuf, Bpl, T);
    grid.sync();

    // ---- P2: agg layer 0 ----
    for (int tile = blk; tile < AG_CNT; tile += nblk) {
        agg_tile(tile, tid, hbuf, Bpl, fwd_nbr, rev_nbr, Wcp, bc,
                 ybuf, bns, bns + 128, Spack);
        __syncthreads();
    }
    grid.sync();

    // ---- P3: BN finalize (l0) + layer-1 B planes ----
    if (tid < 128) {
        float mu = bns[tid] * (1.f / NN);
        float var = bns[128 + tid] * (1.f / NN) - mu * mu;
        float s = bn_g[tid] * rsqrtf(var + 1e-5f);
        sc[tid] = s;
        sh[tid] = bn_b[tid] - mu * s;
    }
    __syncthreads();
    for (int rt = blk * 8 + wv; rt < RT_CNT; rt += nblk * 8)
        preB_wave(rt, lane, ybuf, sc, sh, hbuf,
                  WbBD + (size_t)2 * 128 * 128, Bpl, T);
    grid.sync();

    // ---- P4: agg layer 1 ----
    for (int tile = blk; tile < AG_CNT; tile += nblk) {
        agg_tile(tile, tid, hbuf, Bpl, fwd_nbr, rev_nbr,
                 Wcp + (size_t)KSTEPS * 32 * 128, bc + 128,
                 ybuf, bns + 256, bns + 384, Spack);
        __syncthreads();
    }
    grid.sync();

    // ---- P5: BN finalize (l1) + MLP head ----
    if (tid < 128) {
        float mu = bns[256 + tid] * (1.f / NN);
        float var = bns[384 + tid] * (1.f / NN) - mu * mu;
        float s = bn_g[128 + tid] * rsqrtf(var + 1e-5f);
        sc[tid] = s;
        sh[tid] = bn_b[128 + tid] - mu * s;
    }
    __syncthreads();
    for (int rt = blk * 8 + wv; rt < RT_CNT; rt += nblk * 8)
        mlp_wave(rt, lane, ybuf, sc, sh, W1p, b1, W2p, b2, out, T);
}

// ---------------------------------------------------------------------------
extern "C" void kernel_launch(void* const* d_in, const int* in_sizes, int n_in,
                              void* d_out, int out_size, void* d_ws, size_t ws_size,
                              hipStream_t stream) {
    const float* x      = (const float*)d_in[0];
    const float* W_in   = (const float*)d_in[1];
    const float* b_in   = (const float*)d_in[2];
    const float* pre_W  = (const float*)d_in[3];
    const float* pre_b  = (const float*)d_in[4];
    const float* post_W = (const float*)d_in[5];
    const float* post_b = (const float*)d_in[6];
    const float* lin_W  = (const float*)d_in[7];
    const float* lin_b  = (const float*)d_in[8];
    const float* bn_g   = (const float*)d_in[9];
    const float* bn_b   = (const float*)d_in[10];
    const float* mlp_W1 = (const float*)d_in[11];
    const float* mlp_b1 = (const float*)d_in[12];
    const float* mlp_W2 = (const float*)d_in[13];
    const float* mlp_b2 = (const float*)d_in[14];
    const int*   edge   = (const int*)d_in[15];
    float* out = (float*)d_out;

    char* w = (char*)d_ws;
    const size_t plane = (size_t)NN * 128 * sizeof(float);       // 25.6 MB
    __half* hbuf = (__half*)w; w += plane / 2;                   // f16
    float* ybuf = (float*)w; w += plane;
    __half* Bpl = (__half*)w; w += plane;                        // both rels, f16
    int* rev_nbr = (int*)w; w += (size_t)NN * DEG * sizeof(int);
    // ---- zeroed region (single memset): cnt | Qw | bc | bns ----
    char* zbase = w;
    int* cnt     = (int*)w; w += (size_t)NN * sizeof(int);
    float* Qw    = (float*)w; w += (size_t)2 * 128 * 128 * sizeof(float);
    float* bc    = (float*)w; w += 2 * 128 * sizeof(float);
    float* bns   = (float*)w; w += 4 * 128 * sizeof(float);
    size_t zsize = (size_t)(w - zbase);
    // ---- packed weights ----
    __half* Wcp  = (__half*)w; w += (size_t)2 * KSTEPS * 32 * 128 * sizeof(__half);
    __half* Winp = (__half*)w; w += (size_t)128 * 128 * sizeof(__half);
    __half* W1p  = (__half*)w; w += (size_t)128 * 128 * sizeof(__half);
    __half* W2p  = (__half*)w; w += (size_t)128 * 32 * sizeof(__half);
    __half* WbBD = (__half*)w; w += (size_t)4 * 128 * 128 * sizeof(__half);

    const int* fwd_nbr = edge;  // dst sorted => fwd list d = src[8d..8d+8]

    (void)hipMemsetAsync(zbase, 0, zsize, stream);
    k_wprep<<<16, 256, 0, stream>>>(post_W, pre_W, pre_b, post_b, lin_W, lin_b,
                                    Wcp, Qw, bc);
    k_prep2<<<BUILD_BLKS + 66, 256, 0, stream>>>(
        edge, cnt, rev_nbr, Qw, Wcp, W_in, Winp, mlp_W1, W1p,
        mlp_W2, W2p, pre_W, WbBD);

    int maxActive = 0;
    (void)hipOccupancyMaxActiveBlocksPerMultiprocessor(&maxActive, k_mega, 512, 0);
    if (maxActive < 1) maxActive = 1;
    int gridN = maxActive * 256;
    if (gridN > 512) gridN = 512;

    void* kargs[] = {
        (void*)&x, (void*)&Winp, (void*)&b_in, (void*)&WbBD,
        (void*)&hbuf, (void*)&Bpl, (void*)&Wcp,
        (void*)&fwd_nbr, (void*)&rev_nbr,
        (void*)&bc, (void*)&ybuf, (void*)&bns, (void*)&bn_g, (void*)&bn_b,
        (void*)&W1p, (void*)&mlp_b1, (void*)&W2p, (void*)&mlp_b2, (void*)&out
    };
    (void)hipLaunchCooperativeKernel((void*)k_mega, dim3(gridN), dim3(512),
                                     kargs, 0, stream);
}

// Round 14
// 397.296 us; speedup vs baseline: 1.5019x; 1.5019x over previous
//
#include <hip/hip_runtime.h>
#include <hip/hip_fp16.h>
#include <cstddef>
#include <cstdint>

#define NN 50000
#define DEG 8
#define EE (NN*DEG)
#define RT_CNT 3125   // NN/16 row-tiles
#define AG_CNT 1563   // ceil(NN/32) 32-row tiles for k_agg_gemm
#define KSTEPS 36     // K=1152 / 32:  [xt(4) | rel*16+tw*4+{Bm,mn,mx,std}]
#define W8L 18432     // Wcp layer stride in short8 units (KSTEPS*32*128/8)
#define MPAD 132      // f16 tile row pad (halves)
#define BUILD_BLKS 1563   // ceil(EE/256)

typedef __attribute__((ext_vector_type(8))) short short8;
typedef __attribute__((ext_vector_type(4))) float f32x4;

union Pack8 { __half h[8]; __half2 h2[4]; uint4 u; short8 s8; };

// ---------------------------------------------------------------------------
// K0w: combined-weight prep. 4 slice-blocks per m4 (64 blocks total). Each
// slice recomputes the cheap LDS prep (deterministic) and owns 1/4 of the
// heavy output loops (Wcp pack u-range, Qw i-range). bc: slice 0 only.
// ---------------------------------------------------------------------------
__global__ __launch_bounds__(256) void k_wprep(
    const float* __restrict__ post_W, const float* __restrict__ pre_W,
    const float* __restrict__ pre_b, const float* __restrict__ post_b,
    const float* __restrict__ lin_W, const float* __restrict__ lin_b,
    __half* __restrict__ Wcp, float* __restrict__ Qw, float* __restrict__ bc) {
    __shared__ float Pf[160 * 33];
    __shared__ float Wl[32 * 128];
    __shared__ float Wt[32 * 32];
    __shared__ float Ps[32 * 32];
    __shared__ float Q[32 * 32];
    __shared__ float T3s[32];
    int tid = threadIdx.x;
    int m4 = blockIdx.x >> 2;
    int slice = blockIdx.x & 3;
    int l = m4 >> 3, r = (m4 >> 2) & 1, tw = m4 & 3;
    const float* PW = post_W + (size_t)m4 * 416 * 32;
    for (int i = tid; i < 160 * 32; i += 256) {
        int row = i >> 5, g = i & 31;
        float v;
        if (row < 32) v = PW[row * 32 + g];
        else {
            int rr = row - 32;
            v = PW[(32 + rr) * 32 + g] + PW[(160 + rr) * 32 + g] + PW[(288 + rr) * 32 + g];
        }
        Pf[row * 33 + g] = v;
    }
    for (int i = tid; i < 1024; i += 256) Wt[i] = pre_W[(size_t)m4 * 2048 + i];
    for (int i = tid; i < 4096; i += 256)
        Wl[i] = lin_W[(size_t)(l * 2 + r) * 16384 + tw * 32 * 128 + i];
    __syncthreads();
    for (int i = tid; i < 1024; i += 256) {
        int g = i >> 5, j = i & 31;
        Ps[i] = Pf[(32 + g) * 33 + j] + Pf[(64 + g) * 33 + j] + Pf[(96 + g) * 33 + j];
    }
    __syncthreads();
    for (int i = tid; i < 1024; i += 256) {
        int f = i >> 5, j = i & 31;
        float acc = Pf[f * 33 + j];
#pragma unroll
        for (int g = 0; g < 32; g++) acc += Wt[f * 32 + g] * Ps[g * 32 + j];
        Q[i] = acc;
    }
    if (slice == 0 && tid < 32) {
        int j = tid;
        float v = post_b[m4 * 32 + j];
#pragma unroll
        for (int g = 0; g < 32; g++) v += pre_b[m4 * 32 + g] * Ps[g * 32 + j];
        T3s[j] = v;
    }
    __syncthreads();
    // Wcp pack: this slice owns u in [slice*512, slice*512+512)
    for (int u = slice * 512 + tid; u < slice * 512 + 512; u += 256) {
        int lane = u & 63, t = (u >> 6) & 7, s = u >> 9;
        int quad = lane >> 4, nl = lane & 15;
        int n = t * 16 + nl;
        Pack8 pk;
#pragma unroll
        for (int e = 0; e < 8; e++) {
            int f = quad * 8 + e;
            const float* Pr = &Pf[((s + 1) * 32 + f) * 33];
            float acc = 0.f;
#pragma unroll
            for (int j = 0; j < 32; j++) acc += Pr[j] * Wl[j * 128 + n];
            pk.h[e] = __float2half(acc);
        }
        int ks = 4 + r * 16 + tw * 4 + s;
        *(uint4*)&Wcp[((size_t)l * W8L + (t * KSTEPS + ks) * 64 + lane) * 8] = pk.u;
    }
    // Qw scatter: this slice owns i in [slice*1024, slice*1024+1024)
    for (int i = slice * 1024 + tid; i < slice * 1024 + 1024; i += 256) {
        int f = i >> 7, n = i & 127;
        float acc = 0.f;
#pragma unroll
        for (int j = 0; j < 32; j++) acc += Q[f * 32 + j] * Wl[j * 128 + n];
        atomicAdd(&Qw[(size_t)l * 16384 + (tw * 32 + f) * 128 + n], acc);
    }
    if (slice == 0 && tid < 128) {
        float v = 0.f;
#pragma unroll
        for (int j = 0; j < 32; j++) v += T3s[j] * Wl[j * 128 + tid];
        atomicAdd(&bc[l * 128 + tid], v);
        if ((m4 & 7) == 0)
            atomicAdd(&bc[l * 128 + tid],
                      lin_b[(2 * l) * 128 + tid] + lin_b[(2 * l + 1) * 128 + tid]);
    }
}

// ---------------------------------------------------------------------------
// K_prep2: merged rev-neighbor build + all weight packs (R18 verbatim)
// ---------------------------------------------------------------------------
__global__ void k_prep2(const int* __restrict__ ef, int* __restrict__ cnt,
                        int* __restrict__ rev_nbr,
                        const float* __restrict__ Qw, __half* __restrict__ Wcp,
                        const float* __restrict__ W_in, __half* __restrict__ Winp,
                        const float* __restrict__ mlp_W1, __half* __restrict__ W1p,
                        const float* __restrict__ mlp_W2, __half* __restrict__ W2p,
                        const float* __restrict__ pre_W, __half* __restrict__ WbBD) {
    int b = blockIdx.x, tid = threadIdx.x;
    if (b < BUILD_BLKS) {
        int e = b * 256 + tid;
        if (e < EE) {
            int s = ef[e], d = ef[EE + e];
            int q = atomicAdd(&cnt[s], 1);
            rev_nbr[s * DEG + q] = d;
        }
        return;
    }
    int gid = (b - BUILD_BLKS) * 256 + tid;
    if (gid < 4096) {
        int lane = gid & 63, t = (gid >> 6) & 7, ks = (gid >> 9) & 3, l = gid >> 11;
        int quad = lane >> 4;
        int n = t * 16 + (lane & 15);
        Pack8 pk;
#pragma unroll
        for (int e = 0; e < 8; e++)
            pk.h[e] = __float2half(Qw[(size_t)l * 16384 + (ks * 32 + quad * 8 + e) * 128 + n]);
        *(uint4*)&Wcp[((size_t)l * W8L + (t * KSTEPS + ks) * 64 + lane) * 8] = pk.u;
        return;
    }
    if (gid < 8704) {
        const float* W; __half* dst; int id;
        if (gid < 6144)      { W = W_in;   dst = Winp; id = gid - 4096; }
        else if (gid < 8192) { W = mlp_W1; dst = W1p;  id = gid - 6144; }
        else                 { W = mlp_W2; dst = W2p;  id = gid - 8192; }
        int N = (gid < 8192) ? 128 : 32;
        int lane = id & 63;
        int ks = (id >> 6) & 3;
        int t = (id >> 6) >> 2;
        int quad = lane >> 4, nl = lane & 15;
        int n = t * 16 + nl;
        Pack8 pk;
#pragma unroll
        for (int e = 0; e < 8; e++)
            pk.h[e] = __float2half(W[(size_t)(ks * 32 + quad * 8 + e) * N + n]);
        *(uint4*)&dst[(size_t)id * 8] = pk.u;
        return;
    }
    {
        int id = gid - 8704;
        if (id >= 8192) return;
        int lane = id & 63, ks = (id >> 6) & 3, t8 = (id >> 8) & 7;
        int rel = (id >> 11) & 1, l = id >> 12;
        int quad = lane >> 4, nl = lane & 15;
        int n = t8 * 16 + nl;
        int tn = n >> 5;
        Pack8 pk;
#pragma unroll
        for (int e = 0; e < 8; e++) {
            int k = ks * 32 + quad * 8 + e;
            float v = 0.f;
            if ((k >> 5) == tn)
                v = pre_W[(size_t)((((l * 2 + rel) * 4 + tn) * 64) + 32 + (k & 31)) * 32 + (n & 31)];
            pk.h[e] = __float2half(v);
        }
        *(uint4*)&WbBD[((size_t)(l * 2 + rel) * 2048 + (t8 * 4 + ks) * 64 + lane) * 8] = pk.u;
    }
}

// ---------------------------------------------------------------------------
// K1f: FUSED input layer + layer-0 B planes (R18 verbatim)
// ---------------------------------------------------------------------------
__global__ __launch_bounds__(256) void k_in_fused(
    const float* __restrict__ X, const __half* __restrict__ Wp,
    const float* __restrict__ b, const __half* __restrict__ WbBDp,
    __half* __restrict__ H, __half* __restrict__ Bplanes) {
    __shared__ __half Sh[4][16 * MPAD];
    int tid = threadIdx.x, wv = tid >> 6, lane = tid & 63;
    int rt = blockIdx.x * 4 + wv;
    if (rt >= RT_CNT) rt = RT_CNT - 1;  // duplicate work, benign
    int mm = lane & 15, quad = lane >> 4;
    short8 a[4];
#pragma unroll
    for (int ks = 0; ks < 4; ks++) {
        const float4* p = (const float4*)&X[(size_t)(rt * 16 + mm) * 128 + ks * 32 + quad * 8];
        float4 v0 = p[0], v1 = p[1];
        Pack8 pk;
        pk.h[0] = __float2half(v0.x); pk.h[1] = __float2half(v0.y);
        pk.h[2] = __float2half(v0.z); pk.h[3] = __float2half(v0.w);
        pk.h[4] = __float2half(v1.x); pk.h[5] = __float2half(v1.y);
        pk.h[6] = __float2half(v1.z); pk.h[7] = __float2half(v1.w);
        a[ks] = pk.s8;
    }
    const short8* Bb = (const short8*)Wp + lane;
    f32x4 acc[8];
#pragma unroll
    for (int t = 0; t < 8; t++) acc[t] = (f32x4){0.f, 0.f, 0.f, 0.f};
#pragma unroll
    for (int ks = 0; ks < 4; ks++)
#pragma unroll
        for (int t = 0; t < 8; t++)
            acc[t] = __builtin_amdgcn_mfma_f32_16x16x32_f16(
                a[ks], Bb[(t * 4 + ks) * 64], acc[t], 0, 0, 0);
    __half* T = Sh[wv];
#pragma unroll
    for (int t = 0; t < 8; t++) {
        int n = t * 16 + mm;
        float bias = b[n];
#pragma unroll
        for (int r = 0; r < 4; r++)
            T[(quad * 4 + r) * MPAD + n] = __float2half(fmaxf(acc[t][r] + bias, 0.f));
    }
#pragma unroll
    for (int it = 0; it < 4; it++) {
        int idx = it * 64 + lane;
        int row = idx >> 4, col = (idx & 15) * 8;
        *(uint4*)&H[(size_t)(rt * 16 + row) * 128 + col] = *(uint4*)&T[row * MPAD + col];
    }
    short8 a2[4];
#pragma unroll
    for (int ks = 0; ks < 4; ks++)
        a2[ks] = *(const short8*)&T[mm * MPAD + ks * 32 + quad * 8];
#pragma unroll
    for (int rel = 0; rel < 2; rel++) {
        const short8* Bd = (const short8*)WbBDp + (size_t)rel * 2048 + lane;
        f32x4 ac[8];
#pragma unroll
        for (int t = 0; t < 8; t++) ac[t] = (f32x4){0.f, 0.f, 0.f, 0.f};
#pragma unroll
        for (int ks = 0; ks < 4; ks++)
#pragma unroll
            for (int t = 0; t < 8; t++)
                ac[t] = __builtin_amdgcn_mfma_f32_16x16x32_f16(
                    a2[ks], Bd[(t * 4 + ks) * 64], ac[t], 0, 0, 0);
#pragma unroll
        for (int t = 0; t < 8; t++) {
            int n = t * 16 + mm;
#pragma unroll
            for (int r = 0; r < 4; r++)
                T[(quad * 4 + r) * MPAD + n] = __float2half(ac[t][r]);
        }
        __half* Bp = Bplanes + (size_t)rel * NN * 128;
#pragma unroll
        for (int it = 0; it < 4; it++) {
            int idx = it * 64 + lane;
            int row = idx >> 4, col = (idx & 15) * 8;
            *(uint4*)&Bp[(size_t)(rt * 16 + row) * 128 + col] = *(uint4*)&T[row * MPAD + col];
        }
    }
}

// ---------------------------------------------------------------------------
// K2: B planes via MFMA vs block-diag packed pre_W (V=2 only; R18 verbatim)
// ---------------------------------------------------------------------------
template<int V>
__global__ __launch_bounds__(256) void k_preB_mfma(
    const __half* __restrict__ Hin, const float* __restrict__ Yf,
    const float* __restrict__ bns, const float* __restrict__ bns2,
    const float* __restrict__ gamma, const float* __restrict__ beta,
    __half* __restrict__ Hout, const __half* __restrict__ WbBDp,
    __half* __restrict__ Bplanes) {
    __shared__ __half Sh[4][16 * MPAD];
    __shared__ float sc[128], sh[128];
    int tid = threadIdx.x, wv = tid >> 6, lane = tid & 63;
    int rt = blockIdx.x * 4 + wv;
    if (rt >= RT_CNT) rt = RT_CNT - 1;
    if (V == 2) {
        if (tid < 128) {
            float mu = bns[tid] * (1.f / NN);
            float var = bns2[tid] * (1.f / NN) - mu * mu;
            float s = gamma[tid] * rsqrtf(var + 1e-5f);
            sc[tid] = s;
            sh[tid] = beta[tid] - mu * s;
        }
        __syncthreads();
    }
    int mm = lane & 15, quad = lane >> 4;
    short8 a[4];
#pragma unroll
    for (int ks = 0; ks < 4; ks++) {
        int c0 = ks * 32 + quad * 8;
        size_t base = (size_t)(rt * 16 + mm) * 128 + c0;
        if (V == 1) {
            Pack8 pk; pk.u = *(const uint4*)&Hin[base];
            a[ks] = pk.s8;
        } else {
            const float4* p = (const float4*)&Yf[base];
            float4 v0 = p[0], v1 = p[1];
            float4 s0 = *(const float4*)&sc[c0], s1 = *(const float4*)&sc[c0 + 4];
            float4 f0 = *(const float4*)&sh[c0], f1 = *(const float4*)&sh[c0 + 4];
            Pack8 pk;
            pk.h[0] = __float2half(fmaxf(s0.x * v0.x + f0.x, 0.f));
            pk.h[1] = __float2half(fmaxf(s0.y * v0.y + f0.y, 0.f));
            pk.h[2] = __float2half(fmaxf(s0.z * v0.z + f0.z, 0.f));
            pk.h[3] = __float2half(fmaxf(s0.w * v0.w + f0.w, 0.f));
            pk.h[4] = __float2half(fmaxf(s1.x * v1.x + f1.x, 0.f));
            pk.h[5] = __float2half(fmaxf(s1.y * v1.y + f1.y, 0.f));
            pk.h[6] = __float2half(fmaxf(s1.z * v1.z + f1.z, 0.f));
            pk.h[7] = __float2half(fmaxf(s1.w * v1.w + f1.w, 0.f));
            *(uint4*)&Hout[base] = pk.u;
            a[ks] = pk.s8;
        }
    }
    __half* T = Sh[wv];
#pragma unroll
    for (int rel = 0; rel < 2; rel++) {
        const short8* Bb = (const short8*)WbBDp + (size_t)rel * 2048 + lane;
        f32x4 acc[8];
#pragma unroll
        for (int t = 0; t < 8; t++) acc[t] = (f32x4){0.f, 0.f, 0.f, 0.f};
#pragma unroll
        for (int ks = 0; ks < 4; ks++)
#pragma unroll
            for (int t = 0; t < 8; t++)
                acc[t] = __builtin_amdgcn_mfma_f32_16x16x32_f16(
                    a[ks], Bb[(t * 4 + ks) * 64], acc[t], 0, 0, 0);
#pragma unroll
        for (int t = 0; t < 8; t++) {
            int n = t * 16 + mm;
#pragma unroll
            for (int r = 0; r < 4; r++)
                T[(quad * 4 + r) * MPAD + n] = __float2half(acc[t][r]);
        }
        __half* Bp = Bplanes + (size_t)rel * NN * 128;
#pragma unroll
        for (int it = 0; it < 4; it++) {
            int idx = it * 64 + lane;
            int row = idx >> 4, col = (idx & 15) * 8;
            *(uint4*)&Bp[(size_t)(rt * 16 + row) * 128 + col] = *(uint4*)&T[row * MPAD + col];
        }
    }
}

// ---------------------------------------------------------------------------
// K3: FUSED gather+stats+MFMA-GEMM (R14 structure; fwd_nbr = edge directly)
// ---------------------------------------------------------------------------
__global__ __launch_bounds__(512) void k_agg_gemm(
    const __half* __restrict__ hbuf, const __half* __restrict__ Bplanes,
    const int* __restrict__ fwd_nbr, const int* __restrict__ rev_nbr,
    const __half* __restrict__ Wcp, const float* __restrict__ bc,
    float* __restrict__ Y, float* __restrict__ bnsum, float* __restrict__ bnsum2) {
    __shared__ __half Spack[32 * 128 * 8];  // 65,536 B
    int tid = threadIdx.x;
    int blk = blockIdx.x;
    int lane = tid & 63, wv = tid >> 6;
    int G = tid >> 4;
    int f16 = tid & 15;
    int tw = f16 >> 2, quad = f16 & 3;
    int fo = f16 * 8;
    int pos = quad * 32 + (G ^ quad ^ ((tw & 1) << 2));
    int mB = lane & 15, qB = lane >> 4;
    int t = wv;
    int nodeg = blk * 32 + G;
    if (nodeg >= NN) nodeg = NN - 1;

    Pack8 axt[2][4];
#pragma unroll
    for (int mt = 0; mt < 2; mt++) {
        int nd = blk * 32 + mt * 16 + mB;
        if (nd >= NN) nd = NN - 1;
#pragma unroll
        for (int ks = 0; ks < 4; ks++)
            axt[mt][ks].u = *(const uint4*)&hbuf[(size_t)nd * 128 + ks * 32 + qB * 8];
    }
    {
        const int4* nf = (const int4*)&fwd_nbr[nodeg * 8];
        const int4* nr = (const int4*)&rev_nbr[nodeg * 8];
        int4 a0 = nf[0], a1 = nf[1], b0v = nr[0], b1v = nr[1];
        int idx0[8] = {a0.x, a0.y, a0.z, a0.w, a1.x, a1.y, a1.z, a1.w};
        int idx1[8] = {b0v.x, b0v.y, b0v.z, b0v.w, b1v.x, b1v.y, b1v.z, b1v.w};
        Pack8 r0[8], r1[8];
        const __half* Bp1 = Bplanes + (size_t)NN * 128;
#pragma unroll
        for (int k = 0; k < 8; k++)
            r0[k].u = *(const uint4*)&Bplanes[(size_t)idx0[k] * 128 + fo];
#pragma unroll
        for (int k = 0; k < 8; k++)
            r1[k].u = *(const uint4*)&Bp1[(size_t)idx1[k] * 128 + fo];
#pragma unroll
        for (int rel = 0; rel < 2; rel++) {
            Pack8* rr = rel ? r1 : r0;
            float sS[8], qS[8], mnS[8], mxS[8];
#pragma unroll
            for (int j = 0; j < 8; j++) {
                sS[j] = 0.f; qS[j] = 0.f; mnS[j] = 1e30f; mxS[j] = -1e30f;
            }
#pragma unroll
            for (int k = 0; k < 8; k++) {
#pragma unroll
                for (int j2 = 0; j2 < 4; j2++) {
                    __half2 h = rr[k].h2[j2];
                    float a = __half2float(__low2half(h));
                    float b = __half2float(__high2half(h));
                    int j0 = 2 * j2, j1 = j0 + 1;
                    sS[j0] += a; qS[j0] += a * a;
                    mnS[j0] = fminf(mnS[j0], a); mxS[j0] = fmaxf(mxS[j0], a);
                    sS[j1] += b; qS[j1] += b * b;
                    mnS[j1] = fminf(mnS[j1], b); mxS[j1] = fmaxf(mxS[j1], b);
                }
            }
            Pack8 mean, stdv, mnp, mxp;
#pragma unroll
            for (int j = 0; j < 8; j++) {
                float Bm = sS[j] * 0.125f;
                mean.h[j] = __float2half(Bm);
                stdv.h[j] = __float2half(
                    sqrtf(fmaxf(qS[j] * 0.125f - Bm * Bm, 0.f) + 1e-5f));
                mnp.h[j] = __float2half(mnS[j]);
                mxp.h[j] = __float2half(mxS[j]);
            }
            int ksb = rel * 16 + tw * 4;
            *(uint4*)&Spack[((size_t)(ksb + 0) * 128 + pos) * 8] = mean.u;
            *(uint4*)&Spack[((size_t)(ksb + 1) * 128 + pos) * 8] = mnp.u;
            *(uint4*)&Spack[((size_t)(ksb + 2) * 128 + pos) * 8] = mxp.u;
            *(uint4*)&Spack[((size_t)(ksb + 3) * 128 + pos) * 8] = stdv.u;
        }
    }
    __syncthreads();
    const short8* Bb = (const short8*)Wcp + lane;
    f32x4 acc0 = (f32x4){0.f, 0.f, 0.f, 0.f};
    f32x4 acc1 = (f32x4){0.f, 0.f, 0.f, 0.f};
    short8 p[6];
#pragma unroll
    for (int dd = 0; dd < 6; dd++) p[dd] = Bb[((size_t)t * KSTEPS + dd) * 64];
    __builtin_amdgcn_s_setprio(1);
#pragma unroll
    for (int ks = 0; ks < KSTEPS; ks++) {
        short8 a0f, a1f;
        if (ks < 4) {
            a0f = axt[0][ks].s8;
            a1f = axt[1][ks].s8;
        } else {
            int ss = ks - 4;
            int twk = (ss >> 2) & 3;
            int posr = qB * 32 + (mB ^ qB ^ ((twk & 1) << 2));
            const __half* row = &Spack[((size_t)ss * 128 + posr) * 8];
            a0f = *(const short8*)row;
            a1f = *(const short8*)(row + 16 * 8);
        }
        acc0 = __builtin_amdgcn_mfma_f32_16x16x32_f16(a0f, p[ks % 6], acc0, 0, 0, 0);
        acc1 = __builtin_amdgcn_mfma_f32_16x16x32_f16(a1f, p[ks % 6], acc1, 0, 0, 0);
        if (ks + 6 < KSTEPS) p[ks % 6] = Bb[((size_t)t * KSTEPS + ks + 6) * 64];
    }
    __builtin_amdgcn_s_setprio(0);
#pragma unroll
    for (int mt = 0; mt < 2; mt++) {
        f32x4 acc = mt ? acc1 : acc0;
        int n = t * 16 + mB;
        float bias = bc[n];
        float ls = 0.f, ls2 = 0.f;
#pragma unroll
        for (int r = 0; r < 4; r++) {
            int node = blk * 32 + mt * 16 + qB * 4 + r;
            if (node < NN) {
                float v = acc[r] + bias;
                Y[(size_t)node * 128 + n] = v;
                ls += v; ls2 += v * v;
            }
        }
        ls += __shfl_xor(ls, 16); ls += __shfl_xor(ls, 32);
        ls2 += __shfl_xor(ls2, 16); ls2 += __shfl_xor(ls2, 32);
        if (qB == 0) {
            atomicAdd(&bnsum[n], ls);
            atomicAdd(&bnsum2[n], ls2);
        }
    }
}

// ---------------------------------------------------------------------------
// K7: fused BN(inline finalize)+relu+MLP via MFMA (R18 verbatim)
// ---------------------------------------------------------------------------
__global__ __launch_bounds__(256) void k_mlp_mfma(
    const float* __restrict__ Yb, const float* __restrict__ bns,
    const float* __restrict__ bns2, const float* __restrict__ gamma,
    const float* __restrict__ beta, const __half* __restrict__ W1p,
    const float* __restrict__ b1, const __half* __restrict__ W2p,
    const float* __restrict__ b2, float* __restrict__ out) {
    __shared__ __half Sh[4][16 * MPAD];
    __shared__ float sc[128], sh[128];
    int tid = threadIdx.x, wv = tid >> 6, lane = tid & 63;
    int rt = blockIdx.x * 4 + wv;
    if (rt >= RT_CNT) rt = RT_CNT - 1;
    if (tid < 128) {
        float mu = bns[tid] * (1.f / NN);
        float var = bns2[tid] * (1.f / NN) - mu * mu;
        float s = gamma[tid] * rsqrtf(var + 1e-5f);
        sc[tid] = s;
        sh[tid] = beta[tid] - mu * s;
    }
    __syncthreads();
    int mm = lane & 15, quad = lane >> 4;
    short8 a[4];
#pragma unroll
    for (int ks = 0; ks < 4; ks++) {
        int c0 = ks * 32 + quad * 8;
        const float4* p = (const float4*)&Yb[(size_t)(rt * 16 + mm) * 128 + c0];
        float4 v0 = p[0], v1 = p[1];
        float4 s0 = *(const float4*)&sc[c0], s1 = *(const float4*)&sc[c0 + 4];
        float4 f0 = *(const float4*)&sh[c0], f1 = *(const float4*)&sh[c0 + 4];
        Pack8 pk;
        pk.h[0] = __float2half(fmaxf(s0.x * v0.x + f0.x, 0.f));
        pk.h[1] = __float2half(fmaxf(s0.y * v0.y + f0.y, 0.f));
        pk.h[2] = __float2half(fmaxf(s0.z * v0.z + f0.z, 0.f));
        pk.h[3] = __float2half(fmaxf(s0.w * v0.w + f0.w, 0.f));
        pk.h[4] = __float2half(fmaxf(s1.x * v1.x + f1.x, 0.f));
        pk.h[5] = __float2half(fmaxf(s1.y * v1.y + f1.y, 0.f));
        pk.h[6] = __float2half(fmaxf(s1.z * v1.z + f1.z, 0.f));
        pk.h[7] = __float2half(fmaxf(s1.w * v1.w + f1.w, 0.f));
        a[ks] = pk.s8;
    }
    const short8* B1 = (const short8*)W1p + lane;
    f32x4 acc[8];
#pragma unroll
    for (int t = 0; t < 8; t++) acc[t] = (f32x4){0.f, 0.f, 0.f, 0.f};
#pragma unroll
    for (int ks = 0; ks < 4; ks++)
#pragma unroll
        for (int t = 0; t < 8; t++)
            acc[t] = __builtin_amdgcn_mfma_f32_16x16x32_f16(
                a[ks], B1[(t * 4 + ks) * 64], acc[t], 0, 0, 0);
    __half* T = Sh[wv];
#pragma unroll
    for (int t = 0; t < 8; t++) {
        int n = t * 16 + mm;
        float bias = b1[n];
#pragma unroll
        for (int r = 0; r < 4; r++)
            T[(quad * 4 + r) * MPAD + n] = __float2half(fmaxf(acc[t][r] + bias, 0.f));
    }
    short8 a2[4];
#pragma unroll
    for (int ks = 0; ks < 4; ks++)
        a2[ks] = *(const short8*)&T[mm * MPAD + ks * 32 + quad * 8];
    const short8* B2 = (const short8*)W2p + lane;
    f32x4 acc2[2];
#pragma unroll
    for (int t = 0; t < 2; t++) acc2[t] = (f32x4){0.f, 0.f, 0.f, 0.f};
#pragma unroll
    for (int ks = 0; ks < 4; ks++)
#pragma unroll
        for (int t = 0; t < 2; t++)
            acc2[t] = __builtin_amdgcn_mfma_f32_16x16x32_f16(
                a2[ks], B2[(t * 4 + ks) * 64], acc2[t], 0, 0, 0);
#pragma unroll
    for (int t = 0; t < 2; t++) {
        int n = t * 16 + mm;
        float bias = b2[n];
#pragma unroll
        for (int r = 0; r < 4; r++)
            out[(size_t)(rt * 16 + quad * 4 + r) * 32 + n] = acc2[t][r] + bias;
    }
}

// ---------------------------------------------------------------------------
extern "C" void kernel_launch(void* const* d_in, const int* in_sizes, int n_in,
                              void* d_out, int out_size, void* d_ws, size_t ws_size,
                              hipStream_t stream) {
    const float* x      = (const float*)d_in[0];
    const float* W_in   = (const float*)d_in[1];
    const float* b_in   = (const float*)d_in[2];
    const float* pre_W  = (const float*)d_in[3];
    const float* pre_b  = (const float*)d_in[4];
    const float* post_W = (const float*)d_in[5];
    const float* post_b = (const float*)d_in[6];
    const float* lin_W  = (const float*)d_in[7];
    const float* lin_b  = (const float*)d_in[8];
    const float* bn_g   = (const float*)d_in[9];
    const float* bn_b   = (const float*)d_in[10];
    const float* mlp_W1 = (const float*)d_in[11];
    const float* mlp_b1 = (const float*)d_in[12];
    const float* mlp_W2 = (const float*)d_in[13];
    const float* mlp_b2 = (const float*)d_in[14];
    const int*   edge   = (const int*)d_in[15];
    float* out = (float*)d_out;

    char* w = (char*)d_ws;
    const size_t plane = (size_t)NN * 128 * sizeof(float);       // 25.6 MB
    __half* hbuf = (__half*)w; w += plane / 2;                   // f16
    float* ybuf = (float*)w; w += plane;
    __half* Bpl = (__half*)w; w += plane;                        // both rels, f16
    int* rev_nbr = (int*)w; w += (size_t)NN * DEG * sizeof(int);
    // ---- zeroed region (single memset): cnt | Qw | bc | bns ----
    char* zbase = w;
    int* cnt     = (int*)w; w += (size_t)NN * sizeof(int);
    float* Qw    = (float*)w; w += (size_t)2 * 128 * 128 * sizeof(float);
    float* bc    = (float*)w; w += 2 * 128 * sizeof(float);
    float* bns   = (float*)w; w += 4 * 128 * sizeof(float);  // pairs: l0(s,s2), l1(s,s2)
    size_t zsize = (size_t)(w - zbase);
    // ---- packed weights ----
    __half* Wcp  = (__half*)w; w += (size_t)2 * KSTEPS * 32 * 128 * sizeof(__half);
    __half* Winp = (__half*)w; w += (size_t)128 * 128 * sizeof(__half);
    __half* W1p  = (__half*)w; w += (size_t)128 * 128 * sizeof(__half);
    __half* W2p  = (__half*)w; w += (size_t)128 * 32 * sizeof(__half);
    __half* WbBD = (__half*)w; w += (size_t)4 * 128 * 128 * sizeof(__half);

    const int gWave = (RT_CNT + 3) / 4;  // 782 blocks, 4 waves each
    const int* fwd_nbr = edge;           // dst sorted => fwd list d = src[8d..8d+8]

    (void)hipMemsetAsync(zbase, 0, zsize, stream);
    k_wprep<<<64, 256, 0, stream>>>(post_W, pre_W, pre_b, post_b, lin_W, lin_b,
                                    Wcp, Qw, bc);
    k_prep2<<<BUILD_BLKS + 66, 256, 0, stream>>>(
        edge, cnt, rev_nbr, Qw, Wcp, W_in, Winp, mlp_W1, W1p,
        mlp_W2, W2p, pre_W, WbBD);

    // h = relu(x @ W_in + b_in)  (MFMA, f16 out) + fused layer-0 B planes
    k_in_fused<<<gWave, 256, 0, stream>>>(x, Winp, b_in, WbBD, hbuf, Bpl);

    // layer 0
    k_agg_gemm<<<AG_CNT, 512, 0, stream>>>(
        hbuf, Bpl, fwd_nbr, rev_nbr, Wcp, bc, ybuf, bns, bns + 128);
    // layer 1 (inline BN-final of layer 0)
    k_preB_mfma<2><<<gWave, 256, 0, stream>>>(
        nullptr, ybuf, bns, bns + 128, bn_g, bn_b, hbuf,
        WbBD + (size_t)2 * 128 * 128, Bpl);
    k_agg_gemm<<<AG_CNT, 512, 0, stream>>>(
        hbuf, Bpl, fwd_nbr, rev_nbr, Wcp + (size_t)KSTEPS * 32 * 128,
        bc + 128, ybuf, bns + 256, bns + 384);

    // out = relu(bn_relu(y) @ mlp_W1 + b1) @ mlp_W2 + b2  (inline BN-final l1)
    k_mlp_mfma<<<gWave, 256, 0, stream>>>(ybuf, bns + 256, bns + 384,
                                          bn_g + 128, bn_b + 128,
                                          W1p, mlp_b1, W2p, mlp_b2, out);
}